// Round 2
// baseline (741.137 us; speedup 1.0000x reference)
//
#include <hip/hip_runtime.h>
#include <stdint.h>

typedef unsigned long long u64;

// workspace layout (bytes)
//  g      : u8  [16][512][512]           @ 0        (4 MiB)
//  magdir : u16 [16][512][512]           @ 4 MiB    (8 MiB)   mag(11b) | dir<<12
//  weak   : u64 [16][512][8]             @ 12 MiB   (512 KiB)
//  strong : u64 [16][512][8]             @ 12.5 MiB (512 KiB)
//  edge   : u64 [16][512][8]             @ 13 MiB   (512 KiB)
#define MD_OFF   (4ull << 20)
#define WK_OFF   (12ull << 20)
#define ST_OFF   ((12ull << 20) + (512ull << 10))
#define ED_OFF   ((12ull << 20) + (1024ull << 10))

// ---------------- K1: gray = floor(clip(0.2989 x0 + 0.587 x1 + 0.114 x2)) ----
__global__ __launch_bounds__(256) void k_gray(const float* __restrict__ x,
                                              unsigned char* __restrict__ g) {
#pragma clang fp contract(off)
    const float C0 = (float)0.2989, C1 = (float)0.587, C2 = (float)0.114;
    int i   = blockIdx.x * 256 + threadIdx.x;   // 1,048,576 quads total
    int b   = i >> 16;                          // 65536 quads / image
    int rem = i & 65535;                        // h*128 + wq
    const float* xb = x + (size_t)b * 786432 + (size_t)rem * 4;
    float4 r0 = *(const float4*)(xb);
    float4 r1 = *(const float4*)(xb + 262144);
    float4 r2 = *(const float4*)(xb + 524288);
    float g0 = C0 * r0.x + C1 * r1.x + C2 * r2.x;   // ((a+b)+c) like numpy
    float g1 = C0 * r0.y + C1 * r1.y + C2 * r2.y;
    float g2 = C0 * r0.z + C1 * r1.z + C2 * r2.z;
    float g3 = C0 * r0.w + C1 * r1.w + C2 * r2.w;
    g0 = floorf(fminf(fmaxf(g0, 0.0f), 255.0f));
    g1 = floorf(fminf(fmaxf(g1, 0.0f), 255.0f));
    g2 = floorf(fminf(fmaxf(g2, 0.0f), 255.0f));
    g3 = floorf(fminf(fmaxf(g3, 0.0f), 255.0f));
    uchar4 st = make_uchar4((unsigned char)g0, (unsigned char)g1,
                            (unsigned char)g2, (unsigned char)g3);
    *(uchar4*)(g + (size_t)b * 262144 + (size_t)rem * 4) = st;
}

// ---------------- K2: Sobel (edge-replicate pad), mag = |gx|+|gy|, dir code --
__global__ __launch_bounds__(256) void k_sobel(const unsigned char* __restrict__ g,
                                               unsigned short* __restrict__ magdir) {
    const float TG22f = (float)0.4142135623730951;
    const float TG67f = (float)2.414213562373095;
    int i = blockIdx.x * 256 + threadIdx.x;     // 4,194,304 pixels
    int b = i >> 18;
    int r = (i >> 9) & 511;
    int w = i & 511;
    const unsigned char* gb = g + (size_t)b * 262144;
    int rm = r > 0 ? r - 1 : 0, rp = r < 511 ? r + 1 : 511;
    int wm = w > 0 ? w - 1 : 0, wp = w < 511 ? w + 1 : 511;
    int a00 = gb[rm * 512 + wm], a01 = gb[rm * 512 + w], a02 = gb[rm * 512 + wp];
    int a10 = gb[r  * 512 + wm],                          a12 = gb[r  * 512 + wp];
    int a20 = gb[rp * 512 + wm], a21 = gb[rp * 512 + w],  a22 = gb[rp * 512 + wp];
    int gx = a02 + 2 * a12 + a22 - a00 - 2 * a10 - a20;
    int gy = a20 + 2 * a21 + a22 - a00 - 2 * a01 - a02;
    int ax = gx < 0 ? -gx : gx;
    int ay = gy < 0 ? -gy : gy;
    int mag = ax + ay;                           // <= 2040, exact
    float fax = (float)ax, fay = (float)ay;
    unsigned dir;
    if (fay <= TG22f * fax)      dir = 0u;                       // horiz
    else if (fay > TG67f * fax)  dir = 1u;                       // vert
    else                         dir = (gx * gy >= 0) ? 2u : 3u; // diag
    magdir[i] = (unsigned short)(mag | (dir << 12));
}

// ---------------- K3: NMS + thresholds, ballot-pack weak/strong bitmasks -----
__global__ __launch_bounds__(256) void k_nms(const unsigned short* __restrict__ magdir,
                                             u64* __restrict__ weakw,
                                             u64* __restrict__ strongw) {
    int i = blockIdx.x * 256 + threadIdx.x;
    int b = i >> 18;
    int r = (i >> 9) & 511;
    int w = i & 511;
    const unsigned short* mb = magdir + (size_t)b * 262144;
    int md  = mb[r * 512 + w];
    int mag = md & 0x7FF;
    int dir = md >> 12;
    auto ldm = [&](int rr, int ww) -> int {
        if ((unsigned)rr > 511u || (unsigned)ww > 511u) return 0;  // zero pad
        return (int)(mb[rr * 512 + ww] & 0x7FF);
    };
    int n1, n2;
    if (dir == 0)      { n1 = ldm(r, w + 1);     n2 = ldm(r, w - 1); }
    else if (dir == 1) { n1 = ldm(r - 1, w);     n2 = ldm(r + 1, w); }
    else if (dir == 2) { n1 = ldm(r - 1, w - 1); n2 = ldm(r + 1, w + 1); }
    else               { n1 = ldm(r - 1, w + 1); n2 = ldm(r + 1, w - 1); }
    bool keep = (mag > n1) && (mag >= n2);
    int nms = keep ? mag : 0;
    u64 wb = __ballot(nms > 50);
    u64 sb = __ballot(nms > 150);
    int widx = ((b << 9) + r) * 8 + (w >> 6);
    int lane = threadIdx.x & 63;
    if (lane == 0) weakw[widx]   = wb;
    else if (lane == 1) strongw[widx] = sb;
}

// ---------------- K4: hysteresis, wave-serial raster/anti-raster -------------
// One wave (64 lanes) per image. lane = band*8 + col: band = 64 contiguous
// rows walked serially (register carry), col = one of 8 u64 word-columns.
// Single wave => lockstep, in-order LDS pipe => no barriers needed. Monotone
// chaotic iteration (stale reads are subsets of the fixpoint) => converges to
// the unique fixpoint of  cur |= weak & dilate3x3(cur).
__device__ inline u64 upfill(u64 w, u64 s) {           // s subset of w
    return ((((w + s) ^ w) & w) | s);                  // fill run bits above each seed
}
__device__ inline u64 runfill(u64 w, u64 s) {          // full in-run fill
    u64 u = upfill(w, s);
    u64 d = __brevll(upfill(__brevll(w), __brevll(s)));
    return u | d;
}

__global__ __launch_bounds__(64) void k_hyst(const u64* __restrict__ weakg,
                                             const u64* __restrict__ strongg,
                                             u64* __restrict__ edgeg) {
    __shared__ u64 sw[4096];   // weak, row*8+col
    __shared__ u64 sc[4096];   // cur  (init strong)
    int b = blockIdx.x;
    int t = threadIdx.x;                    // 0..63
    const u64* wk = weakg + (size_t)b * 4096;
    const u64* st = strongg + (size_t)b * 4096;
#pragma unroll 4
    for (int i = 0; i < 64; ++i) {
        int idx = i * 64 + t;               // coalesced
        sw[idx] = wk[idx];
        sc[idx] = st[idx];
    }
    int col  = t & 7;
    int band = t >> 3;
    int rbase = band * 64;
    const bool hasL = col > 0, hasR = col < 7;

    // one row-step: given fresh 'carry' (adjacent row this sweep) and stale
    // 'other' (adjacent row opposite direction), old 'self', weak 'w',
    // compute the new value with full in-row horizontal resolution.
    auto rowstep = [&](u64 w, u64 self, u64 carry, u64 other) -> u64 {
        u64 vert = carry | other;
        u64 lv = __shfl(vert, t - 1);
        u64 rv = __shfl(vert, t + 1);
        u64 dil = vert | (vert << 1) | (vert >> 1)
                | (hasL ? (lv >> 63) : 0) | (hasR ? (rv << 63) : 0);
        u64 nv = runfill(w, self | (w & dil));
        for (;;) {                          // same-row cross-word propagation
            u64 ln = __shfl(nv, t - 1);
            u64 rn = __shfl(nv, t + 1);
            u64 hc = (hasL ? (ln >> 63) : 0) | (hasR ? (rn << 63) : 0);
            u64 add = w & hc & ~nv;
            if (__ballot(add != 0) == 0) break;   // wave-uniform exit
            nv = runfill(w, nv | add);
        }
        return nv;
    };

    for (;;) {
        bool ch = false;
        // ---- DOWN sweep ----
        {
            u64 carry = (rbase > 0) ? sc[(rbase - 1) * 8 + col] : 0;
            u64 self  = sc[rbase * 8 + col];
#pragma unroll 2
            for (int k = 0; k < 64; ++k) {
                int r = rbase + k;
                int idx = r * 8 + col;
                u64 w  = sw[idx];
                u64 dn = (r < 511) ? sc[idx + 8] : 0;   // stale below
                u64 nv = rowstep(w, self, carry, dn);
                if (nv != self) { sc[idx] = nv; ch = true; }
                carry = nv;
                self  = dn;                 // row r+1 old value (we only wrote row r)
            }
        }
        // ---- UP sweep ----
        {
            u64 carry = (rbase + 64 < 512) ? sc[(rbase + 64) * 8 + col] : 0;
            u64 self  = sc[(rbase + 63) * 8 + col];
#pragma unroll 2
            for (int k = 63; k >= 0; --k) {
                int r = rbase + k;
                int idx = r * 8 + col;
                u64 w  = sw[idx];
                u64 up = (r > 0) ? sc[idx - 8] : 0;     // stale above
                u64 nv = rowstep(w, self, carry, up);
                if (nv != self) { sc[idx] = nv; ch = true; }
                carry = nv;
                self  = up;
            }
        }
        if (__ballot(ch) == 0) break;       // wave-uniform fixpoint test
    }

    u64* eg = edgeg + (size_t)b * 4096;
#pragma unroll 4
    for (int i = 0; i < 64; ++i) {
        int idx = i * 64 + t;
        eg[idx] = sc[idx];
    }
}

// ---------------- K5: out[b,o,h,w] = relu(W.[x0,x1,x2,edge] + b) -------------
__global__ __launch_bounds__(256) void k_out(const float* __restrict__ x,
                                             const float* __restrict__ Wm,
                                             const float* __restrict__ bv,
                                             const u64* __restrict__ edgeg,
                                             float* __restrict__ out) {
    __shared__ float sW[128];
    __shared__ float sb[32];
    if (threadIdx.x < 128) sW[threadIdx.x] = Wm[threadIdx.x];
    if (threadIdx.x < 32)  sb[threadIdx.x] = bv[threadIdx.x];
    __syncthreads();
    int i   = blockIdx.x * 256 + threadIdx.x;   // 1,048,576 quads
    int b   = i >> 16;
    int rem = i & 65535;                        // h*128 + wq
    size_t pix = (size_t)rem * 4;               // h*512 + wq*4
    const float* xb = x + (size_t)b * 786432;
    float4 x0 = *(const float4*)(xb + pix);
    float4 x1 = *(const float4*)(xb + 262144 + pix);
    float4 x2 = *(const float4*)(xb + 524288 + pix);
    int r  = rem >> 7;
    int wq = rem & 127;
    u64 ew = edgeg[(((size_t)b * 512 + r) * 8) + (wq >> 4)];
    int sh = (wq & 15) * 4;
    float e0 = ((ew >> (sh + 0)) & 1ull) ? 255.0f : 0.0f;
    float e1 = ((ew >> (sh + 1)) & 1ull) ? 255.0f : 0.0f;
    float e2 = ((ew >> (sh + 2)) & 1ull) ? 255.0f : 0.0f;
    float e3 = ((ew >> (sh + 3)) & 1ull) ? 255.0f : 0.0f;
    float* ob = out + (size_t)b * 32 * 262144 + pix;
#pragma unroll 4
    for (int o = 0; o < 32; ++o) {
        float w0 = sW[o * 4 + 0], w1 = sW[o * 4 + 1];
        float w2 = sW[o * 4 + 2], w3 = sW[o * 4 + 3];
        float bb = sb[o];
        float4 v;
        v.x = fmaxf(w0 * x0.x + w1 * x1.x + w2 * x2.x + w3 * e0 + bb, 0.0f);
        v.y = fmaxf(w0 * x0.y + w1 * x1.y + w2 * x2.y + w3 * e1 + bb, 0.0f);
        v.z = fmaxf(w0 * x0.z + w1 * x1.z + w2 * x2.z + w3 * e2 + bb, 0.0f);
        v.w = fmaxf(w0 * x0.w + w1 * x1.w + w2 * x2.w + w3 * e3 + bb, 0.0f);
        *(float4*)(ob + (size_t)o * 262144) = v;
    }
}

extern "C" void kernel_launch(void* const* d_in, const int* in_sizes, int n_in,
                              void* d_out, int out_size, void* d_ws, size_t ws_size,
                              hipStream_t stream) {
    const float* x  = (const float*)d_in[0];   // (16,3,512,512)
    const float* Wm = (const float*)d_in[1];   // (32,4)
    const float* bv = (const float*)d_in[2];   // (32,)
    float* out = (float*)d_out;                // (16,32,512,512)
    char* ws = (char*)d_ws;

    unsigned char*  g      = (unsigned char*)(ws);
    unsigned short* magdir = (unsigned short*)(ws + MD_OFF);
    u64* weakw   = (u64*)(ws + WK_OFF);
    u64* strongw = (u64*)(ws + ST_OFF);
    u64* edgew   = (u64*)(ws + ED_OFF);

    k_gray<<<4096, 256, 0, stream>>>(x, g);
    k_sobel<<<16384, 256, 0, stream>>>(g, magdir);
    k_nms<<<16384, 256, 0, stream>>>(magdir, weakw, strongw);
    k_hyst<<<16, 64, 0, stream>>>(weakw, strongw, edgew);
    k_out<<<4096, 256, 0, stream>>>(x, Wm, bv, edgew, out);
}

// Round 4
// 596.258 us; speedup vs baseline: 1.2430x; 1.2430x over previous
//
#include <hip/hip_runtime.h>
#include <stdint.h>

typedef unsigned long long u64;
typedef float __attribute__((ext_vector_type(4))) fvec4;   // native vec for nontemporal

// workspace layout (bytes)
//  g      : u8  [16][512][512]           @ 0        (4 MiB)
//  magdir : u16 [16][512][512]           @ 4 MiB    (8 MiB)   mag(11b) | dir<<12
//  weak   : u64 [16][512][8]             @ 12 MiB   (512 KiB)
//  strong : u64 [16][512][8]             @ 12.5 MiB (512 KiB)
//  edge   : u64 [16][512][8]             @ 13 MiB   (512 KiB)
#define MD_OFF   (4ull << 20)
#define WK_OFF   (12ull << 20)
#define ST_OFF   ((12ull << 20) + (512ull << 10))
#define ED_OFF   ((12ull << 20) + (1024ull << 10))

// ---------------- K1: gray = floor(clip(0.2989 x0 + 0.587 x1 + 0.114 x2)) ----
__global__ __launch_bounds__(256) void k_gray(const float* __restrict__ x,
                                              unsigned char* __restrict__ g) {
#pragma clang fp contract(off)
    const float C0 = (float)0.2989, C1 = (float)0.587, C2 = (float)0.114;
    int i   = blockIdx.x * 256 + threadIdx.x;   // 1,048,576 quads total
    int b   = i >> 16;                          // 65536 quads / image
    int rem = i & 65535;                        // h*128 + wq
    const float* xb = x + (size_t)b * 786432 + (size_t)rem * 4;
    float4 r0 = *(const float4*)(xb);
    float4 r1 = *(const float4*)(xb + 262144);
    float4 r2 = *(const float4*)(xb + 524288);
    float g0 = C0 * r0.x + C1 * r1.x + C2 * r2.x;   // ((a+b)+c) like numpy
    float g1 = C0 * r0.y + C1 * r1.y + C2 * r2.y;
    float g2 = C0 * r0.z + C1 * r1.z + C2 * r2.z;
    float g3 = C0 * r0.w + C1 * r1.w + C2 * r2.w;
    g0 = floorf(fminf(fmaxf(g0, 0.0f), 255.0f));
    g1 = floorf(fminf(fmaxf(g1, 0.0f), 255.0f));
    g2 = floorf(fminf(fmaxf(g2, 0.0f), 255.0f));
    g3 = floorf(fminf(fmaxf(g3, 0.0f), 255.0f));
    uchar4 st = make_uchar4((unsigned char)g0, (unsigned char)g1,
                            (unsigned char)g2, (unsigned char)g3);
    *(uchar4*)(g + (size_t)b * 262144 + (size_t)rem * 4) = st;
}

// ---------------- K2: Sobel (edge-replicate pad), mag = |gx|+|gy|, dir code --
__global__ __launch_bounds__(256) void k_sobel(const unsigned char* __restrict__ g,
                                               unsigned short* __restrict__ magdir) {
    const float TG22f = (float)0.4142135623730951;
    const float TG67f = (float)2.414213562373095;
    int i = blockIdx.x * 256 + threadIdx.x;     // 4,194,304 pixels
    int b = i >> 18;
    int r = (i >> 9) & 511;
    int w = i & 511;
    const unsigned char* gb = g + (size_t)b * 262144;
    int rm = r > 0 ? r - 1 : 0, rp = r < 511 ? r + 1 : 511;
    int wm = w > 0 ? w - 1 : 0, wp = w < 511 ? w + 1 : 511;
    int a00 = gb[rm * 512 + wm], a01 = gb[rm * 512 + w], a02 = gb[rm * 512 + wp];
    int a10 = gb[r  * 512 + wm],                          a12 = gb[r  * 512 + wp];
    int a20 = gb[rp * 512 + wm], a21 = gb[rp * 512 + w],  a22 = gb[rp * 512 + wp];
    int gx = a02 + 2 * a12 + a22 - a00 - 2 * a10 - a20;
    int gy = a20 + 2 * a21 + a22 - a00 - 2 * a01 - a02;
    int ax = gx < 0 ? -gx : gx;
    int ay = gy < 0 ? -gy : gy;
    int mag = ax + ay;                           // <= 2040, exact
    float fax = (float)ax, fay = (float)ay;
    unsigned dir;
    if (fay <= TG22f * fax)      dir = 0u;                       // horiz
    else if (fay > TG67f * fax)  dir = 1u;                       // vert
    else                         dir = (gx * gy >= 0) ? 2u : 3u; // diag
    magdir[i] = (unsigned short)(mag | (dir << 12));
}

// ---------------- K3: NMS + thresholds, ballot-pack weak/strong bitmasks -----
__global__ __launch_bounds__(256) void k_nms(const unsigned short* __restrict__ magdir,
                                             u64* __restrict__ weakw,
                                             u64* __restrict__ strongw) {
    int i = blockIdx.x * 256 + threadIdx.x;
    int b = i >> 18;
    int r = (i >> 9) & 511;
    int w = i & 511;
    const unsigned short* mb = magdir + (size_t)b * 262144;
    int md  = mb[r * 512 + w];
    int mag = md & 0x7FF;
    int dir = md >> 12;
    auto ldm = [&](int rr, int ww) -> int {
        if ((unsigned)rr > 511u || (unsigned)ww > 511u) return 0;  // zero pad
        return (int)(mb[rr * 512 + ww] & 0x7FF);
    };
    int n1, n2;
    if (dir == 0)      { n1 = ldm(r, w + 1);     n2 = ldm(r, w - 1); }
    else if (dir == 1) { n1 = ldm(r - 1, w);     n2 = ldm(r + 1, w); }
    else if (dir == 2) { n1 = ldm(r - 1, w - 1); n2 = ldm(r + 1, w + 1); }
    else               { n1 = ldm(r - 1, w + 1); n2 = ldm(r + 1, w - 1); }
    bool keep = (mag > n1) && (mag >= n2);
    int nms = keep ? mag : 0;
    u64 wb = __ballot(nms > 50);
    u64 sb = __ballot(nms > 150);
    int widx = ((b << 9) + r) * 8 + (w >> 6);
    int lane = threadIdx.x & 63;
    if (lane == 0) weakw[widx]   = wb;
    else if (lane == 1) strongw[widx] = sb;
}

// ---------------- K4: hysteresis flood fill, block-parallel, padded LDS ------
// One block (1024 thr) per image. thread = stripe(256) x wordcol(8); stripe =
// 4 consecutive rows with register carry, down/up alternating Gauss-Seidel.
// LDS row stride padded 8->9 words to break u64 bank conflicts (8-way -> ~2-4).
// Monotone fixpoint of cur |= weak & dilate3x3(cur): any stale-read order
// converges to the unique fixpoint.
__device__ inline u64 upfill(u64 w, u64 s) {           // s subset of w
    return ((((w + s) ^ w) & w) | s);
}
__device__ inline u64 runfill(u64 w, u64 s) {
    u64 u = upfill(w, s);
    u64 d = __brevll(upfill(__brevll(w), __brevll(s)));
    return u | d;
}

#define HST 9   // padded LDS row stride (words)

__global__ __launch_bounds__(1024) void k_hyst(const u64* __restrict__ weakg,
                                               const u64* __restrict__ strongg,
                                               u64* __restrict__ edgeg) {
    __shared__ u64 sc[512 * HST];   // cur, row*HST+col  (36.9 KiB)
    __shared__ int sflag;
    int b = blockIdx.x;
    int t = threadIdx.x;
    const u64* wk = weakg + (size_t)b * 4096;
    const u64* st = strongg + (size_t)b * 4096;
#pragma unroll
    for (int i = 0; i < 4; ++i) {
        int ig = i * 1024 + t;              // coalesced global
        int r = ig >> 3, c = ig & 7;
        sc[r * HST + c] = st[ig];
    }
    int c  = t & 7;
    int r0 = (t >> 3) * 4;                  // 4 rows per thread
    u64 wreg[4];
#pragma unroll
    for (int j = 0; j < 4; ++j) wreg[j] = wk[(r0 + j) * 8 + c];
    if (t == 0) sflag = 0;
    const bool hasL = c > 0, hasR = c < 7;
    __syncthreads();

    for (;;) {
        bool ch = false;
        // ---- DOWN sweep ----
        {
            u64 carry = (r0 > 0) ? sc[(r0 - 1) * HST + c] : 0;
#pragma unroll
            for (int j = 0; j < 4; ++j) {
                int r = r0 + j;
                int idx = r * HST + c;
                u64 wv = wreg[j];
                u64 self = sc[idx];
                if (self == wv) { carry = self; continue; }
                u64 dm = (r < 511) ? sc[idx + HST] : 0;
                u64 lor = 0, ror_ = 0;
                if (hasL) {
                    u64 lm = sc[idx - 1];
                    u64 lu = (r > 0)   ? sc[idx - HST - 1] : 0;
                    u64 ld = (r < 511) ? sc[idx + HST - 1] : 0;
                    lor = lm | lu | ld;
                }
                if (hasR) {
                    u64 rm = sc[idx + 1];
                    u64 ru = (r > 0)   ? sc[idx - HST + 1] : 0;
                    u64 rd = (r < 511) ? sc[idx + HST + 1] : 0;
                    ror_ = rm | ru | rd;
                }
                u64 vert = carry | dm | self;
                u64 dil = vert | (vert << 1) | (vert >> 1)
                        | (lor >> 63) | (ror_ << 63);
                u64 nv = runfill(wv, self | (wv & dil));
                if (nv != self) { sc[idx] = nv; ch = true; }
                carry = nv;
            }
        }
        // ---- UP sweep ----
        {
            u64 carry = (r0 + 4 < 512) ? sc[(r0 + 4) * HST + c] : 0;
#pragma unroll
            for (int j = 3; j >= 0; --j) {
                int r = r0 + j;
                int idx = r * HST + c;
                u64 wv = wreg[j];
                u64 self = sc[idx];
                if (self == wv) { carry = self; continue; }
                u64 um = (r > 0) ? sc[idx - HST] : 0;
                u64 lor = 0, ror_ = 0;
                if (hasL) {
                    u64 lm = sc[idx - 1];
                    u64 lu = (r > 0)   ? sc[idx - HST - 1] : 0;
                    u64 ld = (r < 511) ? sc[idx + HST - 1] : 0;
                    lor = lm | lu | ld;
                }
                if (hasR) {
                    u64 rm = sc[idx + 1];
                    u64 ru = (r > 0)   ? sc[idx - HST + 1] : 0;
                    u64 rd = (r < 511) ? sc[idx + HST + 1] : 0;
                    ror_ = rm | ru | rd;
                }
                u64 vert = um | carry | self;
                u64 dil = vert | (vert << 1) | (vert >> 1)
                        | (lor >> 63) | (ror_ << 63);
                u64 nv = runfill(wv, self | (wv & dil));
                if (nv != self) { sc[idx] = nv; ch = true; }
                carry = nv;
            }
        }
        if (ch) sflag = 1;
        __syncthreads();
        bool stop = (sflag == 0);
        __syncthreads();                    // all reads done before reset
        if (stop) break;
        if (t == 0) sflag = 0;
        __syncthreads();                    // reset visible before next sweeps
    }

    u64* eg = edgeg + (size_t)b * 4096;
#pragma unroll
    for (int i = 0; i < 4; ++i) {
        int ig = i * 1024 + t;
        int r = ig >> 3, cc = ig & 7;
        eg[ig] = sc[r * HST + cc];
    }
}

// ---------------- K5: out[b,o,h,w] = relu(W.[x0,x1,x2,edge] + b) -------------
__global__ __launch_bounds__(256) void k_out(const float* __restrict__ x,
                                             const float* __restrict__ Wm,
                                             const float* __restrict__ bv,
                                             const u64* __restrict__ edgeg,
                                             float* __restrict__ out) {
    __shared__ float sW[128];
    __shared__ float sb[32];
    if (threadIdx.x < 128) sW[threadIdx.x] = Wm[threadIdx.x];
    if (threadIdx.x < 32)  sb[threadIdx.x] = bv[threadIdx.x];
    __syncthreads();
    int i   = blockIdx.x * 256 + threadIdx.x;   // 1,048,576 quads
    int b   = i >> 16;
    int rem = i & 65535;                        // h*128 + wq
    size_t pix = (size_t)rem * 4;               // h*512 + wq*4
    const float* xb = x + (size_t)b * 786432;
    float4 x0 = *(const float4*)(xb + pix);
    float4 x1 = *(const float4*)(xb + 262144 + pix);
    float4 x2 = *(const float4*)(xb + 524288 + pix);
    int r  = rem >> 7;
    int wq = rem & 127;
    u64 ew = edgeg[(((size_t)b * 512 + r) * 8) + (wq >> 4)];
    int sh = (wq & 15) * 4;
    float e0 = ((ew >> (sh + 0)) & 1ull) ? 255.0f : 0.0f;
    float e1 = ((ew >> (sh + 1)) & 1ull) ? 255.0f : 0.0f;
    float e2 = ((ew >> (sh + 2)) & 1ull) ? 255.0f : 0.0f;
    float e3 = ((ew >> (sh + 3)) & 1ull) ? 255.0f : 0.0f;
    float* ob = out + (size_t)b * 32 * 262144 + pix;
#pragma unroll 8
    for (int o = 0; o < 32; ++o) {
        float w0 = sW[o * 4 + 0], w1 = sW[o * 4 + 1];
        float w2 = sW[o * 4 + 2], w3 = sW[o * 4 + 3];
        float bb = sb[o];
        fvec4 v;
        v.x = fmaxf(w0 * x0.x + w1 * x1.x + w2 * x2.x + w3 * e0 + bb, 0.0f);
        v.y = fmaxf(w0 * x0.y + w1 * x1.y + w2 * x2.y + w3 * e1 + bb, 0.0f);
        v.z = fmaxf(w0 * x0.z + w1 * x1.z + w2 * x2.z + w3 * e2 + bb, 0.0f);
        v.w = fmaxf(w0 * x0.w + w1 * x1.w + w2 * x2.w + w3 * e3 + bb, 0.0f);
        __builtin_nontemporal_store(v, (fvec4*)(ob + (size_t)o * 262144));
    }
}

extern "C" void kernel_launch(void* const* d_in, const int* in_sizes, int n_in,
                              void* d_out, int out_size, void* d_ws, size_t ws_size,
                              hipStream_t stream) {
    const float* x  = (const float*)d_in[0];   // (16,3,512,512)
    const float* Wm = (const float*)d_in[1];   // (32,4)
    const float* bv = (const float*)d_in[2];   // (32,)
    float* out = (float*)d_out;                // (16,32,512,512)
    char* ws = (char*)d_ws;

    unsigned char*  g      = (unsigned char*)(ws);
    unsigned short* magdir = (unsigned short*)(ws + MD_OFF);
    u64* weakw   = (u64*)(ws + WK_OFF);
    u64* strongw = (u64*)(ws + ST_OFF);
    u64* edgew   = (u64*)(ws + ED_OFF);

    k_gray<<<4096, 256, 0, stream>>>(x, g);
    k_sobel<<<16384, 256, 0, stream>>>(g, magdir);
    k_nms<<<16384, 256, 0, stream>>>(magdir, weakw, strongw);
    k_hyst<<<16, 1024, 0, stream>>>(weakw, strongw, edgew);
    k_out<<<4096, 256, 0, stream>>>(x, Wm, bv, edgew, out);
}